// Round 4
// baseline (161.094 us; speedup 1.0000x reference)
//
#include <hip/hip_runtime.h>

// ConnectLoss fused kernel v6 for MI355X (gfx950).
//
// v5 (128.1 us total, absmax 0.0): depth-1 pipelined sections, main ~35 us.
// Still paying 34 float4/wave VMEM issue + 43 transcendentals/px.
// v6: one wave owns TWO adjacent rows (i0, i0+1). The row i0<->i0+1 vertical
// votes reuse in-register sigmoids computed by the own-channel pass (sigma
// strips instead of fast_sig on raw halo loads), and in-row d3/d4 votes do
// the same. Only 3 of 8 directions per px still need halo loads + fast_sig:
// trans/px 43->33, VMEM/px -24%, per-thread ILP x2. sigma-strip substitution
// is bit-identical (fast_sig == sig_sp's sigmoid; sigma(shuffle(x)) ==
// shuffle(sigma(x))). Partials/final layout unchanged from verified v3/v5
// ([6][NBLK] with NBLK=512 now; final kernel loops adapt via macros).

#define HDIM 512
#define WDIM 512
#define HW (HDIM * WDIM)
#define BATCH 8
#define ROWS_PER_BLOCK 8                // 4 waves x 2 rows
#define NBLKX (HDIM / ROWS_PER_BLOCK)   // 64 blocks per batch image
#define NBLK  (NBLKX * BATCH)           // 512 blocks total

__device__ __forceinline__ float fast_sig(float x) {
    float e = __expf(-fabsf(x));
    float r = __builtin_amdgcn_rcpf(1.0f + e);
    return (x >= 0.0f) ? r : e * r;
}
// sigmoid(x); sp_out = log(1+exp(-|x|)) so softplus(+-x) = max(+-x,0) + sp_out
__device__ __forceinline__ float sig_sp(float x, float& sp_out) {
    float e = __expf(-fabsf(x));
    float d = 1.0f + e;
    sp_out = __logf(d);
    float r = __builtin_amdgcn_rcpf(d);
    return (x >= 0.0f) ? r : e * r;
}

struct Arr10 { float v[10]; };  // cols j0-1 .. j0+8 (halos via wave shuffle)

__device__ __forceinline__ void load8(const float* p, float* o) {
    const float4 a = *(const float4*)p;
    const float4 b = *(const float4*)(p + 4);
    o[0]=a.x; o[1]=a.y; o[2]=a.z; o[3]=a.w;
    o[4]=b.x; o[5]=b.y; o[6]=b.z; o[7]=b.w;
}

__device__ __forceinline__ void zero8(float* o) {
#pragma unroll
    for (int k = 0; k < 8; ++k) o[k] = 0.f;
}

__device__ __forceinline__ Arr10 strip10_from(const float* x, int lane) {
    Arr10 r;
    float l = __shfl_up(x[7], 1, 64);
    float h = __shfl_down(x[0], 1, 64);
    r.v[0] = (lane == 0)  ? 0.f : l;    // image-left boundary
    r.v[9] = (lane == 63) ? 0.f : h;    // image-right boundary
#pragma unroll
    for (int k = 0; k < 8; ++k) r.v[k + 1] = x[k];
    return r;
}

__global__ __launch_bounds__(256, 2) void connect_loss_main(
        const float* __restrict__ pred,   // (B, 8, H, W)
        const float* __restrict__ tgt,    // (B, 1, H, W)
        float* __restrict__ partials,     // mode 1: [6][NBLK]
        double* __restrict__ wsd,         // mode 0: 27 doubles
        int mode)
{
    const int b    = blockIdx.y;
    const int tid  = threadIdx.x;
    const int lane = tid & 63;
    const int wv   = tid >> 6;
    const int i0   = blockIdx.x * ROWS_PER_BLOCK + (wv << 1);  // rows i0, i0+1
    const int j0   = lane << 3;
    const int p0   = i0 * WDIM + j0;
    const int p1   = p0 + WDIM;
    const bool rm  = (i0 > 0);                 // row i0-1 exists
    const bool rp  = (i0 + 1 < HDIM - 1);      // row i0+2 exists
    const bool l0  = (lane == 0), l63 = (lane == 63);

    const float* tb = tgt  + (size_t)b * HW;
    const float* pb = pred + (size_t)b * 8 * HW;

    // ---------- prologue loads: 4 target rows + own ch for sections 0,1 +
    // halo rows for section 0. Section s pairs channels (s, 7-s). ----------
    float t0[8], t1[8], t2[8], t3[8];
    zero8(t0); zero8(t3);
    if (rm) load8(tb + p0 - WDIM, t0);
    load8(tb + p0, t1);
    load8(tb + p1, t2);
    if (rp) load8(tb + p1 + WDIM, t3);

    float A0[8], A1[8], A2[8], A3[8];   // set A: chA@i0, chB@i0, chA@i0+1, chB@i0+1
    float B0[8], B1[8], B2[8], B3[8];
    auto ownload = [&](int cA, int cB, float* x0, float* x1, float* x2, float* x3) {
        load8(pb + (size_t)cA * HW + p0, x0);
        load8(pb + (size_t)cB * HW + p0, x1);
        load8(pb + (size_t)cA * HW + p1, x2);
        load8(pb + (size_t)cB * HW + p1, x3);
    };
    float hU[8], hD[8];                 // halo: chB @ i0-1, chA @ i0+2
    auto haloload = [&](int cA, int cB) {
        zero8(hU); zero8(hD);
        if (rm) load8(pb + (size_t)cB * HW + p0 - WDIM, hU);
        if (rp) load8(pb + (size_t)cA * HW + p1 + WDIM, hD);
    };
    ownload(0, 7, A0, A1, A2, A3);      // section 0
    haloload(0, 7);
    ownload(1, 6, B0, B1, B2, B3);      // section 1 (prefetch)

    // ---------- target strips + conn/edge bits (covers pred load latency) --
    Arr10 T0 = strip10_from(t0, lane);
    Arr10 T1 = strip10_from(t1, lane);
    Arr10 T2 = strip10_from(t2, lane);
    Arr10 T3 = strip10_from(t3, lane);

    auto mkbits = [&](const Arr10& m, const Arr10& c, const Arr10& p, int k) -> int {
        const float t_ = c.v[k + 1];
        const float s8 = m.v[k] + m.v[k+1] + m.v[k+2]
                       + c.v[k] + c.v[k+2]
                       + p.v[k] + p.v[k+1] + p.v[k+2];
        const float sc = t_ * s8;
        int bits = (sc < 8.0f && sc > 0.0f) ? 256 : 0;
        if (t_ > 0.5f) {
            bits |= (m.v[k]   > 0.5f ?   1 : 0);
            bits |= (m.v[k+1] > 0.5f ?   2 : 0);
            bits |= (m.v[k+2] > 0.5f ?   4 : 0);
            bits |= (c.v[k]   > 0.5f ?   8 : 0);
            bits |= (c.v[k+2] > 0.5f ?  16 : 0);
            bits |= (p.v[k]   > 0.5f ?  32 : 0);
            bits |= (p.v[k+1] > 0.5f ?  64 : 0);
            bits |= (p.v[k+2] > 0.5f ? 128 : 0);
        }
        return bits;
    };
    int mbp[8];   // row i0 bits in [0:9), row i0+1 bits in [16:25)
#pragma unroll
    for (int k = 0; k < 8; ++k)
        mbp[k] = mkbits(T0, T1, T2, k) | (mkbits(T1, T2, T3, k) << 16);

    float fp0[8], fp1[8], xm0[8], xm1[8], bce = 0.f;
#pragma unroll
    for (int k = 0; k < 8; ++k) {
        fp0[k] = 0.f; fp1[k] = 0.f; xm0[k] = 1e30f; xm1[k] = 1e30f;
    }

    // own-channel math: sigmoid + BCE (logit-space softplus) + xmin
    auto own_ch = [&](int c, int row, const float* x, float* s, float* xm) {
#pragma unroll
        for (int k = 0; k < 8; ++k) {
            float sp;
            const float sv = sig_sp(x[k], sp);
            s[k] = sv;
            xm[k] = fminf(xm[k], x[k]);
            const float sp_pos = fmaxf( x[k], 0.f) + sp;  // softplus(x)
            const float sp_neg = fmaxf(-x[k], 0.f) + sp;  // softplus(-x)
            bce += ((mbp[k] >> (c + (row << 4))) & 1) ? fminf(sp_neg, 100.f)
                                                      : fminf(sp_pos, 100.f);
        }
    };
    // votes: fp[k]=max(fp[k], s[k]*q); raw strip -> fast_sig, sigma strip -> direct
    auto voteRaw = [&](float* fp, const float* s, const Arr10& n, int off, bool rv) {
#pragma unroll
        for (int k = 0; k < 8; ++k) {
            bool ok = rv;
            if (off == 0 && k == 0) ok = ok && !l0;
            if (off == 2 && k == 7) ok = ok && !l63;
            const float q = ok ? fast_sig(n.v[k + off]) : 0.f;
            fp[k] = fmaxf(fp[k], s[k] * q);
        }
    };
    auto voteSig = [&](float* fp, const float* s, const Arr10& n, int off, bool rv) {
#pragma unroll
        for (int k = 0; k < 8; ++k) {
            bool ok = rv;
            if (off == 0 && k == 0) ok = ok && !l0;
            if (off == 2 && k == 7) ok = ok && !l63;
            const float q = ok ? n.v[k + off] : 0.f;
            fp[k] = fmaxf(fp[k], s[k] * q);
        }
    };

    // One section: 4 own-channel passes, then 4 votes. Direction d_cA at
    // row i0 needs chB@i0-1 (halo); at row i0+1 needs chB@i0 (= sB0, shared).
    // Direction d_cB at row i0 needs chA@i0+1 (= sA1, shared); at row i0+1
    // needs chA@i0+2 (halo). offA = col-off of d_cA, offB = of d_cB.
    auto section = [&](int cA, int cB,
                       const float* x0, const float* x1,
                       const float* x2, const float* x3,
                       int offA, int offB) {
        float sA0[8], sB0[8], sA1[8], sB1[8];
        own_ch(cA, 0, x0, sA0, xm0);
        own_ch(cB, 0, x1, sB0, xm0);
        own_ch(cA, 1, x2, sA1, xm1);
        own_ch(cB, 1, x3, sB1, xm1);
        if (cA < 3) {
            Arr10 nU  = strip10_from(hU, lane);
            Arr10 nB0 = strip10_from(sB0, lane);
            Arr10 nA1 = strip10_from(sA1, lane);
            Arr10 nD  = strip10_from(hD, lane);
            voteRaw(fp0, sA0, nU,  offA, rm);     // d_cA @ row i0 (halo up)
            voteSig(fp1, sA1, nB0, offA, true);   // d_cA @ row i0+1 (shared)
            voteSig(fp0, sB0, nA1, offB, true);   // d_cB @ row i0 (shared)
            voteRaw(fp1, sB1, nD,  offB, rp);     // d_cB @ row i0+1 (halo dn)
        } else {  // in-row pair (3,4): d3 off0 uses ch4 sigma, d4 off2 uses ch3
            Arr10 nB0 = strip10_from(sB0, lane);
            Arr10 nA0 = strip10_from(sA0, lane);
            Arr10 nB1 = strip10_from(sB1, lane);
            Arr10 nA1 = strip10_from(sA1, lane);
            voteSig(fp0, sA0, nB0, 0, true);
            voteSig(fp0, sB0, nA0, 2, true);
            voteSig(fp1, sA1, nB1, 0, true);
            voteSig(fp1, sB1, nA1, 2, true);
        }
    };

    // ---------- pipelined sections (col offsets: d0/d1/d2 = 0/1/2,
    // d7/d6/d5 = 2/1/0) ----------
    section(0, 7, A0, A1, A2, A3, 0, 2);
    ownload(2, 5, A0, A1, A2, A3);      // prefetch section 2
    haloload(1, 6);
    section(1, 6, B0, B1, B2, B3, 1, 1);
    ownload(3, 4, B0, B1, B2, B3);      // prefetch section 3 (no halos)
    haloload(2, 5);
    section(2, 5, A0, A1, A2, A3, 2, 0);
    section(3, 4, B0, B1, B2, B3, 0, 2);

    // ---------- epilogue: edge loss + dice partials, both rows ----------
    float e_num = 0.f, e_den = 0.f, inter = 0.f, fpsum = 0.f, tsum = 0.f;
#pragma unroll
    for (int k = 0; k < 8; ++k) {
        {   // row i0
            const float ef = (mbp[k] & 256) ? 1.f : 0.f;
            const float m  = xm0[k];
            float sp;
            const float pmin = sig_sp(m, sp);
            e_num += ef * fminf(fmaxf(m, 0.f) + sp, 100.f);
            e_den += ef * pmin;
            inter += fp0[k] * t1[k];
            fpsum += fp0[k];
            tsum  += t1[k];
        }
        {   // row i0+1
            const float ef = ((mbp[k] >> 16) & 256) ? 1.f : 0.f;
            const float m  = xm1[k];
            float sp;
            const float pmin = sig_sp(m, sp);
            e_num += ef * fminf(fmaxf(m, 0.f) + sp, 100.f);
            e_den += ef * pmin;
            inter += fp1[k] * t2[k];
            fpsum += fp1[k];
            tsum  += t2[k];
        }
    }

    // ---------- block reduction of 6 partials ----------
    float vals[6] = {bce, e_num, e_den, inter, fpsum, tsum};
    __shared__ float red[4][6];
#pragma unroll
    for (int k = 0; k < 6; ++k) {
        float v = vals[k];
#pragma unroll
        for (int o = 32; o > 0; o >>= 1) v += __shfl_down(v, o, 64);
        if (lane == 0) red[wv][k] = v;
    }
    __syncthreads();
    if (tid < 6) {
        const int k = tid;
        const float sum = red[0][k] + red[1][k] + red[2][k] + red[3][k];
        if (mode == 1) {
            partials[k * NBLK + b * NBLKX + blockIdx.x] = sum;
        } else {
            double* dst;
            switch (k) {
                case 0:  dst = wsd + 0;       break;
                case 1:  dst = wsd + 1;       break;
                case 2:  dst = wsd + 2;       break;
                case 3:  dst = wsd + 3 + b;   break;
                case 4:  dst = wsd + 11 + b;  break;
                default: dst = wsd + 19 + b;  break;
            }
            atomicAdd(dst, (double)sum);
        }
    }
}

__global__ __launch_bounds__(256) void connect_loss_final(
        const float* __restrict__ partials,
        const double* __restrict__ wsd,
        float* __restrict__ out, int mode)
{
    __shared__ double red4[4];
    __shared__ double gsum[3];
    __shared__ double bsum[3][BATCH];
    const int t = threadIdx.x;

    if (mode == 1) {
        const int lane = t & 63, wid = t >> 6;
        {   // per-batch categories (k=3,4,5): 8 groups of 32 lanes
            const int g = t >> 5, e = t & 31;
#pragma unroll
            for (int k = 3; k < 6; ++k) {
                double v = 0.0;
                for (int m = e; m < NBLKX; m += 32)
                    v += (double)partials[k * NBLK + g * NBLKX + m];
                for (int o = 16; o > 0; o >>= 1) v += __shfl_down(v, o, 32);
                if (e == 0) bsum[k - 3][g] = v;
            }
        }
        for (int k = 0; k < 3; ++k) {   // global categories
            double v = 0.0;
            for (int idx = t; idx < NBLK; idx += 256)
                v += (double)partials[k * NBLK + idx];
            for (int o = 32; o > 0; o >>= 1) v += __shfl_down(v, o, 64);
            if (lane == 0) red4[wid] = v;
            __syncthreads();
            if (t == 0) gsum[k] = red4[0] + red4[1] + red4[2] + red4[3];
            __syncthreads();
        }
        if (t == 0) {
            const double conn_loss = gsum[0] / (double)((size_t)BATCH * 8 * HW);
            const double edge_loss = gsum[1] / gsum[2];
            double seg = 0.0;
            for (int bb = 0; bb < BATCH; ++bb) {
                const double dice = (2.0 * bsum[0][bb] + 1.0)
                                  / (bsum[1][bb] + bsum[2][bb] + 1.0);
                seg += 1.0 - dice;
            }
            out[0] = (float)(conn_loss + edge_loss + seg / (double)BATCH);
        }
    } else if (t == 0) {
        const double conn_loss = wsd[0] / (double)((size_t)BATCH * 8 * HW);
        const double edge_loss = wsd[1] / wsd[2];
        double seg = 0.0;
        for (int bb = 0; bb < BATCH; ++bb) {
            const double dice = (2.0 * wsd[3 + bb] + 1.0)
                              / (wsd[11 + bb] + wsd[19 + bb] + 1.0);
            seg += 1.0 - dice;
        }
        out[0] = (float)(conn_loss + edge_loss + seg / (double)BATCH);
    }
}

extern "C" void kernel_launch(void* const* d_in, const int* in_sizes, int n_in,
                              void* d_out, int out_size, void* d_ws, size_t ws_size,
                              hipStream_t stream)
{
    const float* pred = (const float*)d_in[0];   // (8, 8, 512, 512)
    const float* tgt  = (const float*)d_in[1];   // (8, 1, 512, 512)
    // d_in[2]/d_in[3] (hori/verti) are exact one-pixel shift permutation
    // matrices -> implemented as index shifts (verified earlier, absmax 0).

    const dim3 grid(NBLKX, BATCH);
    const size_t needA = (size_t)6 * NBLK * sizeof(float);

    if (ws_size >= needA) {
        float* partials = (float*)d_ws;
        connect_loss_main<<<grid, 256, 0, stream>>>(pred, tgt, partials, nullptr, 1);
        connect_loss_final<<<1, 256, 0, stream>>>(partials, nullptr, (float*)d_out, 1);
    } else {
        double* wsd = (double*)d_ws;
        hipMemsetAsync(d_ws, 0, 27 * sizeof(double), stream);
        connect_loss_main<<<grid, 256, 0, stream>>>(pred, tgt, nullptr, wsd, 0);
        connect_loss_final<<<1, 1, 0, stream>>>(nullptr, wsd, (float*)d_out, 0);
    }
}

// Round 5
// 143.676 us; speedup vs baseline: 1.1212x; 1.1212x over previous
//
#include <hip/hip_runtime.h>

// ConnectLoss fused kernel v7 for MI355X (gfx950).
//
// v6 post-mortem: 2-rows-per-wave register sigma-sharing doubled live state,
// spilled to scratch (WRITE_SIZE 62 MB/dispatch, main 69 us). Reverted.
// v7 = v5's verified shell (1 row/wave, 1024 blocks, depth-1 pipelined loads,
// [6][1024] partials; 128.1 us total, absmax 0.0) + LDS sigma-sharing:
// each vertical section writes its own-channel sigmoid rows (computed anyway)
// to a double-buffered 32 KB LDS plane; after one barrier, waves read the
// neighbor ROW's sigma (2x ds_read_b128 + 2-shuffle strip) instead of
// re-loading pred + fast_sig. Only block-boundary rows (wv==0 up / wv==3
// down) keep raw halo loads. In-row pair (3,4) uses register sigma strips.
// Bit-identical: fast_sig(x) == sig_sp(x)'s sigmoid path. Per thread:
// fast_sig 64 -> 12 avg, load8/wave 17 -> 12.5. Section s+1's loads issue
// AFTER barrier s (barrier drains vmcnt(0); issue-before would expose full
// latency), covered by votes(s) + own_ch(s+1).

#define HDIM 512
#define WDIM 512
#define HW (HDIM * WDIM)
#define BATCH 8
#define ROWS_PER_BLOCK 4
#define NBLKX (HDIM / ROWS_PER_BLOCK)   // 128 blocks per batch image
#define NBLK  (NBLKX * BATCH)           // 1024 blocks total

__device__ __forceinline__ float fast_sig(float x) {
    float e = __expf(-fabsf(x));
    float r = __builtin_amdgcn_rcpf(1.0f + e);
    return (x >= 0.0f) ? r : e * r;
}
// sigmoid(x); sp_out = log(1+exp(-|x|)) so softplus(+-x) = max(+-x,0) + sp_out
__device__ __forceinline__ float sig_sp(float x, float& sp_out) {
    float e = __expf(-fabsf(x));
    float d = 1.0f + e;
    sp_out = __logf(d);
    float r = __builtin_amdgcn_rcpf(d);
    return (x >= 0.0f) ? r : e * r;
}

struct Arr10 { float v[10]; };  // cols j0-1 .. j0+8 (halos via wave shuffle)

__device__ __forceinline__ void load8(const float* p, float* o) {
    const float4 a = *(const float4*)p;
    const float4 b = *(const float4*)(p + 4);
    o[0]=a.x; o[1]=a.y; o[2]=a.z; o[3]=a.w;
    o[4]=b.x; o[5]=b.y; o[6]=b.z; o[7]=b.w;
}

__device__ __forceinline__ void zero8(float* o) {
#pragma unroll
    for (int k = 0; k < 8; ++k) o[k] = 0.f;
}

__device__ __forceinline__ Arr10 strip10_from(const float* x, int lane) {
    Arr10 r;
    float l = __shfl_up(x[7], 1, 64);
    float h = __shfl_down(x[0], 1, 64);
    r.v[0] = (lane == 0)  ? 0.f : l;    // image-left boundary
    r.v[9] = (lane == 63) ? 0.f : h;    // image-right boundary
#pragma unroll
    for (int k = 0; k < 8; ++k) r.v[k + 1] = x[k];
    return r;
}

__global__ __launch_bounds__(256) void connect_loss_main(
        const float* __restrict__ pred,   // (B, 8, H, W)
        const float* __restrict__ tgt,    // (B, 1, H, W)
        float* __restrict__ partials,     // mode 1: [6][NBLK]
        double* __restrict__ wsd,         // mode 0: 27 doubles
        int mode)
{
    const int b    = blockIdx.y;
    const int tid  = threadIdx.x;
    const int lane = tid & 63;
    const int wv   = tid >> 6;
    const int i    = blockIdx.x * ROWS_PER_BLOCK + wv;  // wave == one row
    const int j0   = lane << 3;
    const int p0   = i * WDIM + j0;
    const bool rm  = (i > 0), rp = (i < HDIM - 1);
    const bool l0  = (lane == 0), l63 = (lane == 63);
    const bool w0  = (wv == 0), w3 = (wv == ROWS_PER_BLOCK - 1);

    const float* tb = tgt  + (size_t)b * HW;
    const float* pb = pred + (size_t)b * 8 * HW;

    // sigma share: [buf][plane(0=chA,1=chB)][row=wv][col]  (32 KB)
    __shared__ float ssh[2][2][ROWS_PER_BLOCK][WDIM];
    __shared__ float red[4][6];

    // ---------- prologue loads: 3 target rows + own(0,7) + halo0 + own(1,6)
    float t0[8], t1[8], t2[8];
    zero8(t0); zero8(t2);
    if (rm) load8(tb + p0 - WDIM, t0);
    load8(tb + p0, t1);
    if (rp) load8(tb + p0 + WDIM, t2);

    float A0[8], A1[8], B0[8], B1[8];
    auto ownload = [&](int cA, int cB, float* xa, float* xb) {
        load8(pb + (size_t)cA * HW + p0, xa);
        load8(pb + (size_t)cB * HW + p0, xb);
    };
    // halos: only block-boundary waves; hu = chB @ i-1 (wv 0), hd = chA @ i+1 (wv 3)
    float hUa[8], hDa[8], hUb[8], hDb[8];
    zero8(hUa); zero8(hDa); zero8(hUb); zero8(hDb);
    auto haloload = [&](int cA, int cB, float* hu, float* hd) {
        if (w0 && rm) load8(pb + (size_t)cB * HW + p0 - WDIM, hu);
        if (w3 && rp) load8(pb + (size_t)cA * HW + p0 + WDIM, hd);
    };
    ownload(0, 7, A0, A1);
    haloload(0, 7, hUa, hDa);
    ownload(1, 6, B0, B1);

    // ---------- target strips + conn/edge bits (covers pred load latency) --
    Arr10 tm = strip10_from(t0, lane);
    Arr10 tc = strip10_from(t1, lane);
    Arr10 tp = strip10_from(t2, lane);

    int mb[8];
#pragma unroll
    for (int k = 0; k < 8; ++k) {
        const float t_ = tc.v[k + 1];
        const float s8 = tm.v[k] + tm.v[k+1] + tm.v[k+2]
                       + tc.v[k] + tc.v[k+2]
                       + tp.v[k] + tp.v[k+1] + tp.v[k+2];
        const float sc = t_ * s8;
        int bits = (sc < 8.0f && sc > 0.0f) ? 256 : 0;
        if (t_ > 0.5f) {
            bits |= (tm.v[k]   > 0.5f ?   1 : 0);
            bits |= (tm.v[k+1] > 0.5f ?   2 : 0);
            bits |= (tm.v[k+2] > 0.5f ?   4 : 0);
            bits |= (tc.v[k]   > 0.5f ?   8 : 0);
            bits |= (tc.v[k+2] > 0.5f ?  16 : 0);
            bits |= (tp.v[k]   > 0.5f ?  32 : 0);
            bits |= (tp.v[k+1] > 0.5f ?  64 : 0);
            bits |= (tp.v[k+2] > 0.5f ? 128 : 0);
        }
        mb[k] = bits;
    }

    float fp[8], xmin[8], bce = 0.f;
#pragma unroll
    for (int k = 0; k < 8; ++k) { fp[k] = 0.f; xmin[k] = 1e30f; }

    // own-channel math: sigmoid + BCE (logit-space softplus) + xmin
    auto own_ch = [&](int c, const float* x, float* s) {
#pragma unroll
        for (int k = 0; k < 8; ++k) {
            float sp;
            const float sv = sig_sp(x[k], sp);
            s[k] = sv;
            xmin[k] = fminf(xmin[k], x[k]);
            const float sp_pos = fmaxf( x[k], 0.f) + sp;  // softplus(x)
            const float sp_neg = fmaxf(-x[k], 0.f) + sp;  // softplus(-x)
            bce += ((mb[k] >> c) & 1) ? fminf(sp_neg, 100.f)
                                      : fminf(sp_pos, 100.f);
        }
    };
    // votes: fp[k]=max(fp[k], s[k]*q); raw strip -> fast_sig; sigma strip -> direct
    auto voteRaw = [&](const float* s, const Arr10& n, int off, bool rv) {
#pragma unroll
        for (int k = 0; k < 8; ++k) {
            bool ok = rv;
            if (off == 0 && k == 0) ok = ok && !l0;
            if (off == 2 && k == 7) ok = ok && !l63;
            const float q = ok ? fast_sig(n.v[k + off]) : 0.f;
            fp[k] = fmaxf(fp[k], s[k] * q);
        }
    };
    auto voteSig = [&](const float* s, const Arr10& n, int off, bool rv) {
#pragma unroll
        for (int k = 0; k < 8; ++k) {
            bool ok = rv;
            if (off == 0 && k == 0) ok = ok && !l0;
            if (off == 2 && k == 7) ok = ok && !l63;
            const float q = ok ? n.v[k + off] : 0.f;
            fp[k] = fmaxf(fp[k], s[k] * q);
        }
    };

    auto store8 = [&](float* dst, const float* s) {
        *(float4*)dst       = make_float4(s[0], s[1], s[2], s[3]);
        *(float4*)(dst + 4) = make_float4(s[4], s[5], s[6], s[7]);
    };
    auto read8 = [&](const float* src, float* o) {
        const float4 a = *(const float4*)src;
        const float4 c = *(const float4*)(src + 4);
        o[0]=a.x; o[1]=a.y; o[2]=a.z; o[3]=a.w;
        o[4]=c.x; o[5]=c.y; o[6]=c.z; o[7]=c.w;
    };

    // vertical votes for one section: d_cA@row i needs sigma(cB)@i-1 (LDS row
    // wv-1 plane 1, or raw halo for wv==0); d_cB needs sigma(cA)@i+1 (LDS row
    // wv+1 plane 0, or raw halo for wv==3).
    auto vvotes = [&](int buf, const float* sa, const float* sb,
                      int offA, int offB, const float* hu, const float* hd) {
        if (w0) {
            Arr10 nU = strip10_from(hu, lane);
            voteRaw(sa, nU, offA, rm);
        } else {
            float n8[8];
            read8(&ssh[buf][1][wv - 1][j0], n8);
            Arr10 nS = strip10_from(n8, lane);
            voteSig(sa, nS, offA, true);
        }
        if (w3) {
            Arr10 nD = strip10_from(hd, lane);
            voteRaw(sb, nD, offB, rp);
        } else {
            float n8[8];
            read8(&ssh[buf][0][wv + 1][j0], n8);
            Arr10 nS = strip10_from(n8, lane);
            voteSig(sb, nS, offB, true);
        }
    };

    float sa[8], sb[8];
    // ---- section 0: pair (0,7), buf 0, col offsets d0=0, d7=2 ----
    own_ch(0, A0, sa);
    own_ch(7, A1, sb);
    store8(&ssh[0][0][wv][j0], sa);
    store8(&ssh[0][1][wv][j0], sb);
    __syncthreads();
    ownload(2, 5, A0, A1);              // prefetch section 2 (A consumed)
    haloload(1, 6, hUb, hDb);           // halo for section 1
    vvotes(0, sa, sb, 0, 2, hUa, hDa);

    // ---- section 1: pair (1,6), buf 1, offsets d1=1, d6=1 ----
    own_ch(1, B0, sa);
    own_ch(6, B1, sb);
    store8(&ssh[1][0][wv][j0], sa);
    store8(&ssh[1][1][wv][j0], sb);
    __syncthreads();
    ownload(3, 4, B0, B1);              // prefetch section 3 (B consumed)
    haloload(2, 5, hUa, hDa);           // halo for section 2 (hUa free now)
    vvotes(1, sa, sb, 1, 1, hUb, hDb);

    // ---- section 2: pair (2,5), buf 0, offsets d2=2, d5=0 ----
    own_ch(2, A0, sa);
    own_ch(5, A1, sb);
    store8(&ssh[0][0][wv][j0], sa);
    store8(&ssh[0][1][wv][j0], sb);
    __syncthreads();
    vvotes(0, sa, sb, 2, 0, hUa, hDa);

    // ---- section 3: in-row pair (3,4): d3 uses sigma(ch4)@(i,j-1),
    // d4 uses sigma(ch3)@(i,j+1) — register sigma strips, no fast_sig ----
    own_ch(3, B0, sa);
    own_ch(4, B1, sb);
    {
        Arr10 nB = strip10_from(sb, lane);
        Arr10 nA = strip10_from(sa, lane);
        voteSig(sa, nB, 0, true);
        voteSig(sb, nA, 2, true);
    }

    // ---------- epilogue: edge loss + dice partials ----------
    float e_num = 0.f, e_den = 0.f, inter = 0.f, fpsum = 0.f, tsum = 0.f;
#pragma unroll
    for (int k = 0; k < 8; ++k) {
        const float ef = (mb[k] & 256) ? 1.f : 0.f;
        const float m  = xmin[k];
        const float t_ = tc.v[k + 1];
        float sp;
        const float pmin = sig_sp(m, sp);           // sigmoid monotone
        e_num += ef * fminf(fmaxf(m, 0.f) + sp, 100.f);  // softplus(xmin)
        e_den += ef * pmin;
        inter += fp[k] * t_;
        fpsum += fp[k];
        tsum  += t_;
    }

    // ---------- block reduction of 6 partials ----------
    float vals[6] = {bce, e_num, e_den, inter, fpsum, tsum};
#pragma unroll
    for (int k = 0; k < 6; ++k) {
        float v = vals[k];
#pragma unroll
        for (int o = 32; o > 0; o >>= 1) v += __shfl_down(v, o, 64);
        if (lane == 0) red[wv][k] = v;
    }
    __syncthreads();
    if (tid < 6) {
        const int k = tid;
        const float sum = red[0][k] + red[1][k] + red[2][k] + red[3][k];
        if (mode == 1) {
            partials[k * NBLK + b * NBLKX + blockIdx.x] = sum;
        } else {
            double* dst;
            switch (k) {
                case 0:  dst = wsd + 0;       break;
                case 1:  dst = wsd + 1;       break;
                case 2:  dst = wsd + 2;       break;
                case 3:  dst = wsd + 3 + b;   break;
                case 4:  dst = wsd + 11 + b;  break;
                default: dst = wsd + 19 + b;  break;
            }
            atomicAdd(dst, (double)sum);
        }
    }
}

__global__ __launch_bounds__(256) void connect_loss_final(
        const float* __restrict__ partials,
        const double* __restrict__ wsd,
        float* __restrict__ out, int mode)
{
    __shared__ double red4[4];
    __shared__ double gsum[3];
    __shared__ double bsum[3][BATCH];
    const int t = threadIdx.x;

    if (mode == 1) {
        const int lane = t & 63, wid = t >> 6;
        {   // per-batch categories (k=3,4,5): 8 groups of 32 lanes
            const int g = t >> 5, e = t & 31;
#pragma unroll
            for (int k = 3; k < 6; ++k) {
                double v = 0.0;
                for (int m = e; m < NBLKX; m += 32)
                    v += (double)partials[k * NBLK + g * NBLKX + m];
                for (int o = 16; o > 0; o >>= 1) v += __shfl_down(v, o, 32);
                if (e == 0) bsum[k - 3][g] = v;
            }
        }
        for (int k = 0; k < 3; ++k) {   // global categories
            double v = 0.0;
            for (int idx = t; idx < NBLK; idx += 256)
                v += (double)partials[k * NBLK + idx];
            for (int o = 32; o > 0; o >>= 1) v += __shfl_down(v, o, 64);
            if (lane == 0) red4[wid] = v;
            __syncthreads();
            if (t == 0) gsum[k] = red4[0] + red4[1] + red4[2] + red4[3];
            __syncthreads();
        }
        if (t == 0) {
            const double conn_loss = gsum[0] / (double)((size_t)BATCH * 8 * HW);
            const double edge_loss = gsum[1] / gsum[2];
            double seg = 0.0;
            for (int bb = 0; bb < BATCH; ++bb) {
                const double dice = (2.0 * bsum[0][bb] + 1.0)
                                  / (bsum[1][bb] + bsum[2][bb] + 1.0);
                seg += 1.0 - dice;
            }
            out[0] = (float)(conn_loss + edge_loss + seg / (double)BATCH);
        }
    } else if (t == 0) {
        const double conn_loss = wsd[0] / (double)((size_t)BATCH * 8 * HW);
        const double edge_loss = wsd[1] / wsd[2];
        double seg = 0.0;
        for (int bb = 0; bb < BATCH; ++bb) {
            const double dice = (2.0 * wsd[3 + bb] + 1.0)
                              / (wsd[11 + bb] + wsd[19 + bb] + 1.0);
            seg += 1.0 - dice;
        }
        out[0] = (float)(conn_loss + edge_loss + seg / (double)BATCH);
    }
}

extern "C" void kernel_launch(void* const* d_in, const int* in_sizes, int n_in,
                              void* d_out, int out_size, void* d_ws, size_t ws_size,
                              hipStream_t stream)
{
    const float* pred = (const float*)d_in[0];   // (8, 8, 512, 512)
    const float* tgt  = (const float*)d_in[1];   // (8, 1, 512, 512)
    // d_in[2]/d_in[3] (hori/verti) are exact one-pixel shift permutation
    // matrices -> implemented as index shifts (verified earlier, absmax 0).

    const dim3 grid(NBLKX, BATCH);
    const size_t needA = (size_t)6 * NBLK * sizeof(float);

    if (ws_size >= needA) {
        float* partials = (float*)d_ws;
        connect_loss_main<<<grid, 256, 0, stream>>>(pred, tgt, partials, nullptr, 1);
        connect_loss_final<<<1, 256, 0, stream>>>(partials, nullptr, (float*)d_out, 1);
    } else {
        double* wsd = (double*)d_ws;
        hipMemsetAsync(d_ws, 0, 27 * sizeof(double), stream);
        connect_loss_main<<<grid, 256, 0, stream>>>(pred, tgt, nullptr, wsd, 0);
        connect_loss_final<<<1, 1, 0, stream>>>(nullptr, wsd, (float*)d_out, 0);
    }
}

// Round 6
// 139.692 us; speedup vs baseline: 1.1532x; 1.0285x over previous
//
#include <hip/hip_runtime.h>

// ConnectLoss fused kernel v8 for MI355X (gfx950).
//
// v6 (register sigma-share): spilled, 69 us. v7 (LDS sigma-share): barrier
// vmcnt-drain + occupancy collapse, 51 us. Branch abandoned: redundant
// neighbor fast_sig is cheaper than any sharing mechanism tried.
// v8 = v5's verified shell (128.1 us total, main ~35 us, absmax 0.0,
// depth-1 pipelined sections, no LDS staging, no mid-kernel barriers) +
// three low-risk tweaks:
//  1. ROWS_PER_BLOCK 4->2 (128-thr blocks, 2048 blocks = 8/CU): finer
//     scheduling quanta -> less end-of-kernel skew.
//  2. XOR-sign BCE select (sel = x ^ sign-bit) replaces dual softplus+select.
//  3. Split bce accumulator (bce0/bce1) to shorten the 64-add dep chain.

#define HDIM 512
#define WDIM 512
#define HW (HDIM * WDIM)
#define BATCH 8
#define ROWS_PER_BLOCK 2
#define NBLKX (HDIM / ROWS_PER_BLOCK)   // 256 blocks per batch image
#define NBLK  (NBLKX * BATCH)           // 2048 blocks total

__device__ __forceinline__ float fast_sig(float x) {
    float e = __expf(-fabsf(x));
    float r = __builtin_amdgcn_rcpf(1.0f + e);
    return (x >= 0.0f) ? r : e * r;
}
// sigmoid(x); sp_out = log(1+exp(-|x|)) so softplus(+-x) = max(+-x,0) + sp_out
__device__ __forceinline__ float sig_sp(float x, float& sp_out) {
    float e = __expf(-fabsf(x));
    float d = 1.0f + e;
    sp_out = __logf(d);
    float r = __builtin_amdgcn_rcpf(d);
    return (x >= 0.0f) ? r : e * r;
}

struct Arr10 { float v[10]; };  // cols j0-1 .. j0+8 (halos via wave shuffle)

__device__ __forceinline__ void load8(const float* p, float* o) {
    const float4 a = *(const float4*)p;
    const float4 b = *(const float4*)(p + 4);
    o[0]=a.x; o[1]=a.y; o[2]=a.z; o[3]=a.w;
    o[4]=b.x; o[5]=b.y; o[6]=b.z; o[7]=b.w;
}

__device__ __forceinline__ void zero8(float* o) {
#pragma unroll
    for (int k = 0; k < 8; ++k) o[k] = 0.f;
}

__device__ __forceinline__ Arr10 strip10_from(const float* x, int lane) {
    Arr10 r;
    float l = __shfl_up(x[7], 1, 64);
    float h = __shfl_down(x[0], 1, 64);
    r.v[0] = (lane == 0)  ? 0.f : l;    // image-left boundary
    r.v[9] = (lane == 63) ? 0.f : h;    // image-right boundary
#pragma unroll
    for (int k = 0; k < 8; ++k) r.v[k + 1] = x[k];
    return r;
}

__global__ __launch_bounds__(128) void connect_loss_main(
        const float* __restrict__ pred,   // (B, 8, H, W)
        const float* __restrict__ tgt,    // (B, 1, H, W)
        float* __restrict__ partials,     // mode 1: [6][NBLK]
        double* __restrict__ wsd,         // mode 0: 27 doubles
        int mode)
{
    const int b    = blockIdx.y;
    const int tid  = threadIdx.x;
    const int lane = tid & 63;
    const int wv   = tid >> 6;
    const int i    = blockIdx.x * ROWS_PER_BLOCK + wv;  // wave == one row
    const int j0   = lane << 3;
    const int p0   = i * WDIM + j0;
    const bool rm  = (i > 0), rp = (i < HDIM - 1);
    const bool l0  = (lane == 0), l63 = (lane == 63);

    const float* tb = tgt  + (size_t)b * HW;
    const float* pb = pred + (size_t)b * 8 * HW;

    // ---------- issue ALL early loads first: target rows + sections 0,1 ----
    // Section s pairs channels (s, 7-s). Ra = ch(7-s) @ row i-1 (for vote of
    // d_s); Rb = ch(s) @ row i+1 (for vote of d_{7-s}).
    float t0[8], t1[8], t2[8];
    zero8(t0); zero8(t2);
    if (rm) load8(tb + p0 - WDIM, t0);
    load8(tb + p0, t1);
    if (rp) load8(tb + p0 + WDIM, t2);

    float Axa[8], Axb[8], Ara[8], Arb[8];
    float Bxa[8], Bxb[8], Bra[8], Brb[8];

    auto pload = [&](int cA, int cB, float* Xa, float* Xb, float* Ra, float* Rb) {
        load8(pb + (size_t)cA * HW + p0, Xa);
        load8(pb + (size_t)cB * HW + p0, Xb);
        if (rm) load8(pb + (size_t)cB * HW + p0 - WDIM, Ra); else zero8(Ra);
        if (rp) load8(pb + (size_t)cA * HW + p0 + WDIM, Rb); else zero8(Rb);
    };
    pload(0, 7, Axa, Axb, Ara, Arb);        // section 0
    pload(1, 6, Bxa, Bxb, Bra, Brb);        // section 1 (prefetch)

    // ---------- target strips + conn/edge bits (covers pred load latency) --
    Arr10 tm = strip10_from(t0, lane);
    Arr10 tc = strip10_from(t1, lane);
    Arr10 tp = strip10_from(t2, lane);

    int mb[8];
#pragma unroll
    for (int k = 0; k < 8; ++k) {
        const float t_ = tc.v[k + 1];
        const float s8 = tm.v[k] + tm.v[k+1] + tm.v[k+2]
                       + tc.v[k] + tc.v[k+2]
                       + tp.v[k] + tp.v[k+1] + tp.v[k+2];
        const float sc = t_ * s8;
        int bits = (sc < 8.0f && sc > 0.0f) ? 256 : 0;
        if (t_ > 0.5f) {
            bits |= (tm.v[k]   > 0.5f ?   1 : 0);
            bits |= (tm.v[k+1] > 0.5f ?   2 : 0);
            bits |= (tm.v[k+2] > 0.5f ?   4 : 0);
            bits |= (tc.v[k]   > 0.5f ?   8 : 0);
            bits |= (tc.v[k+2] > 0.5f ?  16 : 0);
            bits |= (tp.v[k]   > 0.5f ?  32 : 0);
            bits |= (tp.v[k+1] > 0.5f ?  64 : 0);
            bits |= (tp.v[k+2] > 0.5f ? 128 : 0);
        }
        mb[k] = bits;
    }

    float fp[8], xmin[8], bce0 = 0.f, bce1 = 0.f;
#pragma unroll
    for (int k = 0; k < 8; ++k) { fp[k] = 0.f; xmin[k] = 1e30f; }

    // own-channel math: sigmoid + BCE (logit-space softplus, XOR-sign select)
    // bit c of mb[k] set -> target=1 -> loss = softplus(-x); else softplus(x).
    // sel = x with sign flipped iff bit set; softplus(sel)=max(sel,0)+sp.
    auto own_ch = [&](int c, const float* x, float* s, float& acc) {
#pragma unroll
        for (int k = 0; k < 8; ++k) {
            float sp;
            const float sv = sig_sp(x[k], sp);
            s[k] = sv;
            xmin[k] = fminf(xmin[k], x[k]);
            const int sbit = (mb[k] << (31 - c)) & 0x80000000;
            const float sel = __int_as_float(__float_as_int(x[k]) ^ sbit);
            acc += fminf(fmaxf(sel, 0.f) + sp, 100.f);
        }
    };
    // vote: fp[k] = max(fp[k], s[k] * sigmoid(neigh)); off 0/1/2 = col -1/0/+1
    auto vote = [&](const float* s, const Arr10& n, int off, bool rv) {
#pragma unroll
        for (int k = 0; k < 8; ++k) {
            bool ok = rv;
            if (off == 0 && k == 0) ok = ok && !l0;
            if (off == 2 && k == 7) ok = ok && !l63;
            const float q = ok ? fast_sig(n.v[k + off]) : 0.f;
            fp[k] = fmaxf(fp[k], s[k] * q);
        }
    };
    // one channel-pair section: strips, own math, votes (identical order/math
    // to v5's per-pair blocks, bce split across two accumulators)
    auto section = [&](int cA, int cB, const float* Xa, const float* Xb,
                       const float* Ra, const float* Rb,
                       int offA, int offB, bool gA, bool gB) {
        Arr10 nA = strip10_from(Ra, lane);
        Arr10 nB = strip10_from(Rb, lane);
        float s_a[8], s_b[8];
        own_ch(cA, Xa, s_a, bce0);
        own_ch(cB, Xb, s_b, bce1);
        vote(s_a, nA, offA, gA);
        vote(s_b, nB, offB, gB);
    };

    // ---------- pipelined sections: compute s while s+1 loads are in flight
    section(0, 7, Axa, Axb, Ara, Arb, 0, 2, rm, rp);
    pload(2, 5, Axa, Axb, Ara, Arb);        // section 2 (prefetch into A)
    section(1, 6, Bxa, Bxb, Bra, Brb, 1, 1, rm, rp);
    load8(pb + 3 * (size_t)HW + p0, Bxa);   // section 3: in-row pair (3,4)
    load8(pb + 4 * (size_t)HW + p0, Bxb);
    section(2, 5, Axa, Axb, Ara, Arb, 2, 0, rm, rp);
    section(3, 4, Bxa, Bxb, Bxb, Bxa, 0, 2, true, true);

    // ---------- epilogue: edge loss + dice partials ----------
    float e_num = 0.f, e_den = 0.f, inter = 0.f, fpsum = 0.f, tsum = 0.f;
#pragma unroll
    for (int k = 0; k < 8; ++k) {
        const float ef = (mb[k] & 256) ? 1.f : 0.f;
        const float m  = xmin[k];
        const float t_ = tc.v[k + 1];
        float sp;
        const float pmin = sig_sp(m, sp);           // sigmoid monotone
        e_num += ef * fminf(fmaxf(m, 0.f) + sp, 100.f);  // softplus(xmin)
        e_den += ef * pmin;
        inter += fp[k] * t_;
        fpsum += fp[k];
        tsum  += t_;
    }

    // ---------- block reduction of 6 partials ----------
    float vals[6] = {bce0 + bce1, e_num, e_den, inter, fpsum, tsum};
    __shared__ float red[ROWS_PER_BLOCK][6];
#pragma unroll
    for (int k = 0; k < 6; ++k) {
        float v = vals[k];
#pragma unroll
        for (int o = 32; o > 0; o >>= 1) v += __shfl_down(v, o, 64);
        if (lane == 0) red[wv][k] = v;
    }
    __syncthreads();
    if (tid < 6) {
        const int k = tid;
        const float sum = red[0][k] + red[1][k];
        if (mode == 1) {
            partials[k * NBLK + b * NBLKX + blockIdx.x] = sum;
        } else {
            double* dst;
            switch (k) {
                case 0:  dst = wsd + 0;       break;
                case 1:  dst = wsd + 1;       break;
                case 2:  dst = wsd + 2;       break;
                case 3:  dst = wsd + 3 + b;   break;
                case 4:  dst = wsd + 11 + b;  break;
                default: dst = wsd + 19 + b;  break;
            }
            atomicAdd(dst, (double)sum);
        }
    }
}

__global__ __launch_bounds__(256) void connect_loss_final(
        const float* __restrict__ partials,
        const double* __restrict__ wsd,
        float* __restrict__ out, int mode)
{
    __shared__ double red4[4];
    __shared__ double gsum[3];
    __shared__ double bsum[3][BATCH];
    const int t = threadIdx.x;

    if (mode == 1) {
        const int lane = t & 63, wid = t >> 6;
        {   // per-batch categories (k=3,4,5): 8 groups of 32 lanes
            const int g = t >> 5, e = t & 31;
#pragma unroll
            for (int k = 3; k < 6; ++k) {
                double v = 0.0;
                for (int m = e; m < NBLKX; m += 32)
                    v += (double)partials[k * NBLK + g * NBLKX + m];
                for (int o = 16; o > 0; o >>= 1) v += __shfl_down(v, o, 32);
                if (e == 0) bsum[k - 3][g] = v;
            }
        }
        for (int k = 0; k < 3; ++k) {   // global categories
            double v = 0.0;
            for (int idx = t; idx < NBLK; idx += 256)
                v += (double)partials[k * NBLK + idx];
            for (int o = 32; o > 0; o >>= 1) v += __shfl_down(v, o, 64);
            if (lane == 0) red4[wid] = v;
            __syncthreads();
            if (t == 0) gsum[k] = red4[0] + red4[1] + red4[2] + red4[3];
            __syncthreads();
        }
        if (t == 0) {
            const double conn_loss = gsum[0] / (double)((size_t)BATCH * 8 * HW);
            const double edge_loss = gsum[1] / gsum[2];
            double seg = 0.0;
            for (int bb = 0; bb < BATCH; ++bb) {
                const double dice = (2.0 * bsum[0][bb] + 1.0)
                                  / (bsum[1][bb] + bsum[2][bb] + 1.0);
                seg += 1.0 - dice;
            }
            out[0] = (float)(conn_loss + edge_loss + seg / (double)BATCH);
        }
    } else if (t == 0) {
        const double conn_loss = wsd[0] / (double)((size_t)BATCH * 8 * HW);
        const double edge_loss = wsd[1] / wsd[2];
        double seg = 0.0;
        for (int bb = 0; bb < BATCH; ++bb) {
            const double dice = (2.0 * wsd[3 + bb] + 1.0)
                              / (wsd[11 + bb] + wsd[19 + bb] + 1.0);
            seg += 1.0 - dice;
        }
        out[0] = (float)(conn_loss + edge_loss + seg / (double)BATCH);
    }
}

extern "C" void kernel_launch(void* const* d_in, const int* in_sizes, int n_in,
                              void* d_out, int out_size, void* d_ws, size_t ws_size,
                              hipStream_t stream)
{
    const float* pred = (const float*)d_in[0];   // (8, 8, 512, 512)
    const float* tgt  = (const float*)d_in[1];   // (8, 1, 512, 512)
    // d_in[2]/d_in[3] (hori/verti) are exact one-pixel shift permutation
    // matrices -> implemented as index shifts (verified earlier, absmax 0).

    const dim3 grid(NBLKX, BATCH);
    const size_t needA = (size_t)6 * NBLK * sizeof(float);

    if (ws_size >= needA) {
        float* partials = (float*)d_ws;
        connect_loss_main<<<grid, 128, 0, stream>>>(pred, tgt, partials, nullptr, 1);
        connect_loss_final<<<1, 256, 0, stream>>>(partials, nullptr, (float*)d_out, 1);
    } else {
        double* wsd = (double*)d_ws;
        hipMemsetAsync(d_ws, 0, 27 * sizeof(double), stream);
        connect_loss_main<<<grid, 128, 0, stream>>>(pred, tgt, nullptr, wsd, 0);
        connect_loss_final<<<1, 1, 0, stream>>>(nullptr, wsd, (float*)d_out, 0);
    }
}

// Round 7
// 128.660 us; speedup vs baseline: 1.2521x; 1.0857x over previous
//
#include <hip/hip_runtime.h>

// ConnectLoss fused kernel v9 for MI355X (gfx950).
//
// v8 post-mortem: 128-thread blocks (change 1) regressed main 35->41.5 us
// (doubled per-block fixed costs; skew theory falsified). Reverted.
// v9 = v5's verified shell EXACTLY (ROWS_PER_BLOCK=4, 256-thr blocks, 1024
// blocks, [6][1024] partials, depth-1 pipelined sections; 128.1 us total,
// absmax 0.0) keeping only v8's two micro-tweaks:
//  - XOR-sign BCE select (sel = x ^ sign-bit) replaces dual softplus+select
//    (~6 fewer VALU ops per BCE element, 64/thread).
//  - Split bce accumulator (bce0/bce1) halves the 64-add dep chain.

#define HDIM 512
#define WDIM 512
#define HW (HDIM * WDIM)
#define BATCH 8
#define ROWS_PER_BLOCK 4
#define NBLKX (HDIM / ROWS_PER_BLOCK)   // 128 blocks per batch image
#define NBLK  (NBLKX * BATCH)           // 1024 blocks total

__device__ __forceinline__ float fast_sig(float x) {
    float e = __expf(-fabsf(x));
    float r = __builtin_amdgcn_rcpf(1.0f + e);
    return (x >= 0.0f) ? r : e * r;
}
// sigmoid(x); sp_out = log(1+exp(-|x|)) so softplus(+-x) = max(+-x,0) + sp_out
__device__ __forceinline__ float sig_sp(float x, float& sp_out) {
    float e = __expf(-fabsf(x));
    float d = 1.0f + e;
    sp_out = __logf(d);
    float r = __builtin_amdgcn_rcpf(d);
    return (x >= 0.0f) ? r : e * r;
}

struct Arr10 { float v[10]; };  // cols j0-1 .. j0+8 (halos via wave shuffle)

__device__ __forceinline__ void load8(const float* p, float* o) {
    const float4 a = *(const float4*)p;
    const float4 b = *(const float4*)(p + 4);
    o[0]=a.x; o[1]=a.y; o[2]=a.z; o[3]=a.w;
    o[4]=b.x; o[5]=b.y; o[6]=b.z; o[7]=b.w;
}

__device__ __forceinline__ void zero8(float* o) {
#pragma unroll
    for (int k = 0; k < 8; ++k) o[k] = 0.f;
}

__device__ __forceinline__ Arr10 strip10_from(const float* x, int lane) {
    Arr10 r;
    float l = __shfl_up(x[7], 1, 64);
    float h = __shfl_down(x[0], 1, 64);
    r.v[0] = (lane == 0)  ? 0.f : l;    // image-left boundary
    r.v[9] = (lane == 63) ? 0.f : h;    // image-right boundary
#pragma unroll
    for (int k = 0; k < 8; ++k) r.v[k + 1] = x[k];
    return r;
}

__global__ __launch_bounds__(256) void connect_loss_main(
        const float* __restrict__ pred,   // (B, 8, H, W)
        const float* __restrict__ tgt,    // (B, 1, H, W)
        float* __restrict__ partials,     // mode 1: [6][NBLK]
        double* __restrict__ wsd,         // mode 0: 27 doubles
        int mode)
{
    const int b    = blockIdx.y;
    const int tid  = threadIdx.x;
    const int lane = tid & 63;
    const int wv   = tid >> 6;
    const int i    = blockIdx.x * ROWS_PER_BLOCK + wv;  // wave == one row
    const int j0   = lane << 3;
    const int p0   = i * WDIM + j0;
    const bool rm  = (i > 0), rp = (i < HDIM - 1);
    const bool l0  = (lane == 0), l63 = (lane == 63);

    const float* tb = tgt  + (size_t)b * HW;
    const float* pb = pred + (size_t)b * 8 * HW;

    // ---------- issue ALL early loads first: target rows + sections 0,1 ----
    // Section s pairs channels (s, 7-s). Ra = ch(7-s) @ row i-1 (for vote of
    // d_s); Rb = ch(s) @ row i+1 (for vote of d_{7-s}).
    float t0[8], t1[8], t2[8];
    zero8(t0); zero8(t2);
    if (rm) load8(tb + p0 - WDIM, t0);
    load8(tb + p0, t1);
    if (rp) load8(tb + p0 + WDIM, t2);

    float Axa[8], Axb[8], Ara[8], Arb[8];
    float Bxa[8], Bxb[8], Bra[8], Brb[8];

    auto pload = [&](int cA, int cB, float* Xa, float* Xb, float* Ra, float* Rb) {
        load8(pb + (size_t)cA * HW + p0, Xa);
        load8(pb + (size_t)cB * HW + p0, Xb);
        if (rm) load8(pb + (size_t)cB * HW + p0 - WDIM, Ra); else zero8(Ra);
        if (rp) load8(pb + (size_t)cA * HW + p0 + WDIM, Rb); else zero8(Rb);
    };
    pload(0, 7, Axa, Axb, Ara, Arb);        // section 0
    pload(1, 6, Bxa, Bxb, Bra, Brb);        // section 1 (prefetch)

    // ---------- target strips + conn/edge bits (covers pred load latency) --
    Arr10 tm = strip10_from(t0, lane);
    Arr10 tc = strip10_from(t1, lane);
    Arr10 tp = strip10_from(t2, lane);

    int mb[8];
#pragma unroll
    for (int k = 0; k < 8; ++k) {
        const float t_ = tc.v[k + 1];
        const float s8 = tm.v[k] + tm.v[k+1] + tm.v[k+2]
                       + tc.v[k] + tc.v[k+2]
                       + tp.v[k] + tp.v[k+1] + tp.v[k+2];
        const float sc = t_ * s8;
        int bits = (sc < 8.0f && sc > 0.0f) ? 256 : 0;
        if (t_ > 0.5f) {
            bits |= (tm.v[k]   > 0.5f ?   1 : 0);
            bits |= (tm.v[k+1] > 0.5f ?   2 : 0);
            bits |= (tm.v[k+2] > 0.5f ?   4 : 0);
            bits |= (tc.v[k]   > 0.5f ?   8 : 0);
            bits |= (tc.v[k+2] > 0.5f ?  16 : 0);
            bits |= (tp.v[k]   > 0.5f ?  32 : 0);
            bits |= (tp.v[k+1] > 0.5f ?  64 : 0);
            bits |= (tp.v[k+2] > 0.5f ? 128 : 0);
        }
        mb[k] = bits;
    }

    float fp[8], xmin[8], bce0 = 0.f, bce1 = 0.f;
#pragma unroll
    for (int k = 0; k < 8; ++k) { fp[k] = 0.f; xmin[k] = 1e30f; }

    // own-channel math: sigmoid + BCE (logit-space softplus, XOR-sign select)
    // bit c of mb[k] set -> target=1 -> loss = softplus(-x); else softplus(x).
    // sel = x with sign flipped iff bit set; softplus(sel)=max(sel,0)+sp.
    auto own_ch = [&](int c, const float* x, float* s, float& acc) {
#pragma unroll
        for (int k = 0; k < 8; ++k) {
            float sp;
            const float sv = sig_sp(x[k], sp);
            s[k] = sv;
            xmin[k] = fminf(xmin[k], x[k]);
            const int sbit = (mb[k] << (31 - c)) & 0x80000000;
            const float sel = __int_as_float(__float_as_int(x[k]) ^ sbit);
            acc += fminf(fmaxf(sel, 0.f) + sp, 100.f);
        }
    };
    // vote: fp[k] = max(fp[k], s[k] * sigmoid(neigh)); off 0/1/2 = col -1/0/+1
    auto vote = [&](const float* s, const Arr10& n, int off, bool rv) {
#pragma unroll
        for (int k = 0; k < 8; ++k) {
            bool ok = rv;
            if (off == 0 && k == 0) ok = ok && !l0;
            if (off == 2 && k == 7) ok = ok && !l63;
            const float q = ok ? fast_sig(n.v[k + off]) : 0.f;
            fp[k] = fmaxf(fp[k], s[k] * q);
        }
    };
    // one channel-pair section: strips, own math, votes (identical order/math
    // to v5's per-pair blocks, bce split across two accumulators)
    auto section = [&](int cA, int cB, const float* Xa, const float* Xb,
                       const float* Ra, const float* Rb,
                       int offA, int offB, bool gA, bool gB) {
        Arr10 nA = strip10_from(Ra, lane);
        Arr10 nB = strip10_from(Rb, lane);
        float s_a[8], s_b[8];
        own_ch(cA, Xa, s_a, bce0);
        own_ch(cB, Xb, s_b, bce1);
        vote(s_a, nA, offA, gA);
        vote(s_b, nB, offB, gB);
    };

    // ---------- pipelined sections: compute s while s+1 loads are in flight
    section(0, 7, Axa, Axb, Ara, Arb, 0, 2, rm, rp);
    pload(2, 5, Axa, Axb, Ara, Arb);        // section 2 (prefetch into A)
    section(1, 6, Bxa, Bxb, Bra, Brb, 1, 1, rm, rp);
    load8(pb + 3 * (size_t)HW + p0, Bxa);   // section 3: in-row pair (3,4)
    load8(pb + 4 * (size_t)HW + p0, Bxb);
    section(2, 5, Axa, Axb, Ara, Arb, 2, 0, rm, rp);
    section(3, 4, Bxa, Bxb, Bxb, Bxa, 0, 2, true, true);

    // ---------- epilogue: edge loss + dice partials ----------
    float e_num = 0.f, e_den = 0.f, inter = 0.f, fpsum = 0.f, tsum = 0.f;
#pragma unroll
    for (int k = 0; k < 8; ++k) {
        const float ef = (mb[k] & 256) ? 1.f : 0.f;
        const float m  = xmin[k];
        const float t_ = tc.v[k + 1];
        float sp;
        const float pmin = sig_sp(m, sp);           // sigmoid monotone
        e_num += ef * fminf(fmaxf(m, 0.f) + sp, 100.f);  // softplus(xmin)
        e_den += ef * pmin;
        inter += fp[k] * t_;
        fpsum += fp[k];
        tsum  += t_;
    }

    // ---------- block reduction of 6 partials ----------
    float vals[6] = {bce0 + bce1, e_num, e_den, inter, fpsum, tsum};
    __shared__ float red[4][6];
#pragma unroll
    for (int k = 0; k < 6; ++k) {
        float v = vals[k];
#pragma unroll
        for (int o = 32; o > 0; o >>= 1) v += __shfl_down(v, o, 64);
        if (lane == 0) red[wv][k] = v;
    }
    __syncthreads();
    if (tid < 6) {
        const int k = tid;
        const float sum = red[0][k] + red[1][k] + red[2][k] + red[3][k];
        if (mode == 1) {
            partials[k * NBLK + b * NBLKX + blockIdx.x] = sum;
        } else {
            double* dst;
            switch (k) {
                case 0:  dst = wsd + 0;       break;
                case 1:  dst = wsd + 1;       break;
                case 2:  dst = wsd + 2;       break;
                case 3:  dst = wsd + 3 + b;   break;
                case 4:  dst = wsd + 11 + b;  break;
                default: dst = wsd + 19 + b;  break;
            }
            atomicAdd(dst, (double)sum);
        }
    }
}

__global__ __launch_bounds__(256) void connect_loss_final(
        const float* __restrict__ partials,
        const double* __restrict__ wsd,
        float* __restrict__ out, int mode)
{
    __shared__ double red4[4];
    __shared__ double gsum[3];
    __shared__ double bsum[3][BATCH];
    const int t = threadIdx.x;

    if (mode == 1) {
        const int lane = t & 63, wid = t >> 6;
        {   // per-batch categories (k=3,4,5): 8 groups of 32 lanes
            const int g = t >> 5, e = t & 31;
#pragma unroll
            for (int k = 3; k < 6; ++k) {
                double v = 0.0;
                for (int m = e; m < NBLKX; m += 32)
                    v += (double)partials[k * NBLK + g * NBLKX + m];
                for (int o = 16; o > 0; o >>= 1) v += __shfl_down(v, o, 32);
                if (e == 0) bsum[k - 3][g] = v;
            }
        }
        for (int k = 0; k < 3; ++k) {   // global categories
            double v = 0.0;
            for (int idx = t; idx < NBLK; idx += 256)
                v += (double)partials[k * NBLK + idx];
            for (int o = 32; o > 0; o >>= 1) v += __shfl_down(v, o, 64);
            if (lane == 0) red4[wid] = v;
            __syncthreads();
            if (t == 0) gsum[k] = red4[0] + red4[1] + red4[2] + red4[3];
            __syncthreads();
        }
        if (t == 0) {
            const double conn_loss = gsum[0] / (double)((size_t)BATCH * 8 * HW);
            const double edge_loss = gsum[1] / gsum[2];
            double seg = 0.0;
            for (int bb = 0; bb < BATCH; ++bb) {
                const double dice = (2.0 * bsum[0][bb] + 1.0)
                                  / (bsum[1][bb] + bsum[2][bb] + 1.0);
                seg += 1.0 - dice;
            }
            out[0] = (float)(conn_loss + edge_loss + seg / (double)BATCH);
        }
    } else if (t == 0) {
        const double conn_loss = wsd[0] / (double)((size_t)BATCH * 8 * HW);
        const double edge_loss = wsd[1] / wsd[2];
        double seg = 0.0;
        for (int bb = 0; bb < BATCH; ++bb) {
            const double dice = (2.0 * wsd[3 + bb] + 1.0)
                              / (wsd[11 + bb] + wsd[19 + bb] + 1.0);
            seg += 1.0 - dice;
        }
        out[0] = (float)(conn_loss + edge_loss + seg / (double)BATCH);
    }
}

extern "C" void kernel_launch(void* const* d_in, const int* in_sizes, int n_in,
                              void* d_out, int out_size, void* d_ws, size_t ws_size,
                              hipStream_t stream)
{
    const float* pred = (const float*)d_in[0];   // (8, 8, 512, 512)
    const float* tgt  = (const float*)d_in[1];   // (8, 1, 512, 512)
    // d_in[2]/d_in[3] (hori/verti) are exact one-pixel shift permutation
    // matrices -> implemented as index shifts (verified earlier, absmax 0).

    const dim3 grid(NBLKX, BATCH);
    const size_t needA = (size_t)6 * NBLK * sizeof(float);

    if (ws_size >= needA) {
        float* partials = (float*)d_ws;
        connect_loss_main<<<grid, 256, 0, stream>>>(pred, tgt, partials, nullptr, 1);
        connect_loss_final<<<1, 256, 0, stream>>>(partials, nullptr, (float*)d_out, 1);
    } else {
        double* wsd = (double*)d_ws;
        hipMemsetAsync(d_ws, 0, 27 * sizeof(double), stream);
        connect_loss_main<<<grid, 256, 0, stream>>>(pred, tgt, nullptr, wsd, 0);
        connect_loss_final<<<1, 1, 0, stream>>>(nullptr, wsd, (float*)d_out, 0);
    }
}